// Round 3
// baseline (58.350 us; speedup 1.0000x reference)
//
#include <hip/hip_runtime.h>

// OurButterflyLayer: N=4096, LOGN=12, IN=1024, OUT=4096, BATCH=8192
//
// out[s,j] = sum_{c<1024} input[s,c] * B[or[j],c],  B = M11*...*M0,
// M_i = diag(a_i) + P_i diag(b_i), P_i = xor-perm by (1<<i).
// Elements >=1024 stay zero through stages 0..9 (strides < 1024), and stages
// 10,11 fold into a per-output scale:  out[s,j] = scale[j] * z[src[j]], where
// z = 10-stage butterfly applied to the 1024-float input row.
//
// Round-3 structure: fully independent waves (no barriers, no coeff LDS),
// 2 waves/block, 2 samples/wave, grid 2048 -> 16 waves/CU for phase stagger.
// Coefficients stream through L1/L2 (384 KB total, cache-hot). LDS is only
// the per-wave z scratch for the epilogue gather.

typedef float f4 __attribute__((ext_vector_type(4)));
typedef int   i4 __attribute__((ext_vector_type(4)));

__device__ __forceinline__ int swz(int e) {
    // XOR float-index bits [6:5] into [3:2]: keeps float4 alignment; makes
    // the 64B-stride z writes bank-conflict-free.
    return e ^ (((e >> 5) & 3) << 2);
}

__global__ void __launch_bounds__(256) bfly_prep(
    const float* __restrict__ lp, const int* __restrict__ orow,
    float* __restrict__ scale, int* __restrict__ src)
{
    int j = blockIdx.x * 256 + threadIdx.x;
    if (j >= 4096) return;
    int r = orow[j];
    int c = r & 1023;
    int u = r & 2047;
    const float* A10 = lp + 20 * 4096;
    const float* B10 = lp + 21 * 4096;
    const float* A11 = lp + 22 * 4096;
    const float* B11 = lp + 23 * 4096;
    float f11 = (r & 2048) ? B11[u] : A11[u];
    float f10 = (r & 1024) ? B10[c] : A10[c];
    scale[j] = f11 * f10;
    src[j] = c;
}

__global__ void __launch_bounds__(128, 4) bfly_main(
    const float* __restrict__ inp, const float* __restrict__ lp,
    const float* __restrict__ scale, const int* __restrict__ src,
    float* __restrict__ out)
{
    __shared__ __align__(16) float zbuf[4][1024];   // [wave][sample] scratch
    const int t = threadIdx.x;
    const int wave = t >> 6, lane = t & 63;
    const int s0 = (blockIdx.x * 2 + wave) * 2;     // 2 samples per wave
    float* zw = zbuf[wave * 2];

    float x[2][16];
    #pragma unroll
    for (int m = 0; m < 2; ++m) {
        const f4* p = reinterpret_cast<const f4*>(inp + (size_t)(s0 + m) * 1024 + lane * 16);
        #pragma unroll
        for (int c = 0; c < 4; ++c) {
            f4 v = __builtin_nontemporal_load(p + c);
            x[m][4*c+0] = v.x; x[m][4*c+1] = v.y; x[m][4*c+2] = v.z; x[m][4*c+3] = v.w;
        }
    }

    // stages 0..3: coeff from global (L1-hot), pairs inside the lane's 16 regs
    #pragma unroll
    for (int i = 0; i < 4; ++i) {
        float a[16], b[16];
        const f4* A = reinterpret_cast<const f4*>(lp + (size_t)(2*i)   * 4096 + lane * 16);
        const f4* B = reinterpret_cast<const f4*>(lp + (size_t)(2*i+1) * 4096 + lane * 16);
        #pragma unroll
        for (int c = 0; c < 4; ++c) {
            f4 va = A[c], vb = B[c];
            a[4*c+0]=va.x; a[4*c+1]=va.y; a[4*c+2]=va.z; a[4*c+3]=va.w;
            b[4*c+0]=vb.x; b[4*c+1]=vb.y; b[4*c+2]=vb.z; b[4*c+3]=vb.w;
        }
        const int s = 1 << i;
        #pragma unroll
        for (int m = 0; m < 2; ++m) {
            #pragma unroll
            for (int k = 0; k < 16; ++k) {
                if (!(k & s)) {
                    float lo = x[m][k], hi = x[m][k | s];
                    x[m][k]     = a[k]     * lo + b[k | s] * hi;
                    x[m][k | s] = a[k | s] * hi + b[k]     * lo;
                }
            }
        }
    }

    // stages 4..9: coeff from global, partner value via shfl_xor(lane^d)
    #pragma unroll
    for (int i = 4; i < 10; ++i) {
        const int d = 1 << (i - 4);
        float a[16], b[16];
        const f4* A = reinterpret_cast<const f4*>(lp + (size_t)(2*i)   * 4096 + lane * 16);
        const f4* B = reinterpret_cast<const f4*>(lp + (size_t)(2*i+1) * 4096 + (lane ^ d) * 16);
        #pragma unroll
        for (int c = 0; c < 4; ++c) {
            f4 va = A[c], vb = B[c];
            a[4*c+0]=va.x; a[4*c+1]=va.y; a[4*c+2]=va.z; a[4*c+3]=va.w;
            b[4*c+0]=vb.x; b[4*c+1]=vb.y; b[4*c+2]=vb.z; b[4*c+3]=vb.w;
        }
        #pragma unroll
        for (int m = 0; m < 2; ++m) {
            #pragma unroll
            for (int k = 0; k < 16; ++k) {
                float xp = __shfl_xor(x[m][k], d, 64);
                x[m][k] = a[k] * x[m][k] + b[k] * xp;
            }
        }
    }

    // z -> swizzled LDS (wave-private: in-wave lgkmcnt ordering, no barrier)
    #pragma unroll
    for (int h = 0; h < 2; ++h) {
        const float* xr = x[h];
        #pragma unroll
        for (int c = 0; c < 4; ++c) {
            int e = lane * 16 + 4 * c;
            f4 v = { xr[4*c+0], xr[4*c+1], xr[4*c+2], xr[4*c+3] };
            *reinterpret_cast<f4*>(&zw[h * 1024 + swz(e)]) = v;
        }
    }

    // epilogue: src/scale loaded once, used for both samples
    const i4* srv = reinterpret_cast<const i4*>(src);
    const f4* scv = reinterpret_cast<const f4*>(scale);
    #pragma unroll 4
    for (int it = 0; it < 16; ++it) {
        int j4 = it * 64 + lane;
        i4 si = srv[j4];
        f4 sc = scv[j4];
        #pragma unroll
        for (int h = 0; h < 2; ++h) {
            const float* zh = &zw[h * 1024];
            f4 r;
            r.x = sc.x * zh[swz(si.x)];
            r.y = sc.y * zh[swz(si.y)];
            r.z = sc.z * zh[swz(si.z)];
            r.w = sc.w * zh[swz(si.w)];
            __builtin_nontemporal_store(
                r, reinterpret_cast<f4*>(out + (size_t)(s0 + h) * 4096) + j4);
        }
    }
}

extern "C" void kernel_launch(void* const* d_in, const int* in_sizes, int n_in,
                              void* d_out, int out_size, void* d_ws, size_t ws_size,
                              hipStream_t stream) {
    const float* inp  = (const float*)d_in[0];   // (8192, 1024) f32
    const float* lp   = (const float*)d_in[1];   // (24, 4096)  f32
    const int*   orow = (const int*)d_in[2];     // (4096,)     i32
    float* out = (float*)d_out;                  // (8192, 4096) f32

    float* scale = (float*)d_ws;                       // 4096 f32
    int*   src   = (int*)((char*)d_ws + 4096 * 4);     // 4096 i32

    bfly_prep<<<16, 256, 0, stream>>>(lp, orow, scale, src);
    bfly_main<<<2048, 128, 0, stream>>>(inp, lp, scale, src, out);
}

// Round 4
// 54.395 us; speedup vs baseline: 1.0727x; 1.0727x over previous
//
#include <hip/hip_runtime.h>

// OurButterflyLayer: N=4096, LOGN=12, IN=1024, OUT=4096, BATCH=8192
//
// out[s,j] = scale[j] * z_s[src[j]],  z_s = 10-stage butterfly (stages 0..9)
// applied to the 1024-float input row s; stages 10,11 + out-row gather fold
// into per-output (scale, src) pairs (elements >=1024 stay zero through
// stages 0..9 since strides < 1024 never mix them in).
//
// Round-4 structure: 4 waves/block, coeff for stages 4..9 staged once into
// swizzled LDS (48 KB, persistent), 4 samples/wave processed as two pipelined
// 2-sample passes (stores of pass A overlap compute of pass B). Cross-lane
// exchange d=1,2,8 via DPP (VALU pipe); d=4,16,32 via shfl (DS pipe).

typedef float f4 __attribute__((ext_vector_type(4)));
typedef int   i4 __attribute__((ext_vector_type(4)));

__device__ __forceinline__ int swz(int e) {
    // XOR float-index bits [6:5] into [3:2]: keeps float4 alignment; makes
    // 64B-stride LDS accesses bank-conflict-free.
    return e ^ (((e >> 5) & 3) << 2);
}

template<int CTRL>
__device__ __forceinline__ float dppx(float x) {
    int xi = __builtin_bit_cast(int, x);
    int r  = __builtin_amdgcn_update_dpp(xi, xi, CTRL, 0xF, 0xF, true);
    return __builtin_bit_cast(float, r);
}
// dpp_ctrl: quad_perm(1,0,3,2)=0xB1 (lane^1), quad_perm(2,3,0,1)=0x4E
// (lane^2), row_ror:8=0x128 (lane^8 within 16-lane row).

__global__ void __launch_bounds__(256) bfly_prep(
    const float* __restrict__ lp, const int* __restrict__ orow,
    float* __restrict__ scale, int* __restrict__ src)
{
    int j = blockIdx.x * 256 + threadIdx.x;
    if (j >= 4096) return;
    int r = orow[j];
    int c = r & 1023;
    int u = r & 2047;
    const float* A10 = lp + 20 * 4096;
    const float* B10 = lp + 21 * 4096;
    const float* A11 = lp + 22 * 4096;
    const float* B11 = lp + 23 * 4096;
    float f11 = (r & 2048) ? B11[u] : A11[u];
    float f10 = (r & 1024) ? B10[c] : A10[c];
    scale[j] = f11 * f10;
    src[j] = c;
}

__global__ void __launch_bounds__(256, 2) bfly_main(
    const float* __restrict__ inp, const float* __restrict__ lp,
    const float* __restrict__ scale, const int* __restrict__ src,
    float* __restrict__ out)
{
    __shared__ __align__(16) float cf[12 * 1024];    // stages 4..9 a,b (persistent)
    __shared__ __align__(16) float zbuf[4][2048];    // per-wave z scratch (2 samples)

    const int t = threadIdx.x;
    const int wave = t >> 6, lane = t & 63;
    const int sb = blockIdx.x * 16 + wave * 4;       // wave owns samples sb..sb+3
    float* zw = zbuf[wave];

    float xA[2][16], xB[2][16];

    // issue pass-A input loads first (needed right after the barrier)
    #pragma unroll
    for (int m = 0; m < 2; ++m) {
        const f4* p = reinterpret_cast<const f4*>(inp + (size_t)(sb + m) * 1024 + lane * 16);
        #pragma unroll
        for (int c = 0; c < 4; ++c) {
            f4 v = __builtin_nontemporal_load(p + c);
            xA[m][4*c+0] = v.x; xA[m][4*c+1] = v.y; xA[m][4*c+2] = v.z; xA[m][4*c+3] = v.w;
        }
    }

    // cooperative coeff staging: lp rows 8..19, first 1024 floats of each
    #pragma unroll
    for (int q = 0; q < 12; ++q) {
        const f4 v = *reinterpret_cast<const f4*>(lp + (size_t)(8 + q) * 4096 + t * 4);
        *reinterpret_cast<f4*>(&cf[q * 1024 + swz(t * 4)]) = v;
    }
    __syncthreads();   // cf ready; the only barrier in the kernel

    // pass-B input loads in flight during pass-A compute
    #pragma unroll
    for (int m = 0; m < 2; ++m) {
        const f4* p = reinterpret_cast<const f4*>(inp + (size_t)(sb + 2 + m) * 1024 + lane * 16);
        #pragma unroll
        for (int c = 0; c < 4; ++c) {
            f4 v = __builtin_nontemporal_load(p + c);
            xB[m][4*c+0] = v.x; xB[m][4*c+1] = v.y; xB[m][4*c+2] = v.z; xB[m][4*c+3] = v.w;
        }
    }

    auto butterfly = [&](float (&x)[2][16]) {
        // stages 0..3: coeff from global (L1-hot), pairs inside the 16 regs
        #pragma unroll
        for (int i = 0; i < 4; ++i) {
            float a[16], b[16];
            const f4* A = reinterpret_cast<const f4*>(lp + (size_t)(2*i)   * 4096 + lane * 16);
            const f4* B = reinterpret_cast<const f4*>(lp + (size_t)(2*i+1) * 4096 + lane * 16);
            #pragma unroll
            for (int c = 0; c < 4; ++c) {
                f4 va = A[c], vb = B[c];
                a[4*c+0]=va.x; a[4*c+1]=va.y; a[4*c+2]=va.z; a[4*c+3]=va.w;
                b[4*c+0]=vb.x; b[4*c+1]=vb.y; b[4*c+2]=vb.z; b[4*c+3]=vb.w;
            }
            const int s = 1 << i;
            #pragma unroll
            for (int m = 0; m < 2; ++m) {
                #pragma unroll
                for (int k = 0; k < 16; ++k) {
                    if (!(k & s)) {
                        float lo = x[m][k], hi = x[m][k | s];
                        x[m][k]     = a[k]     * lo + b[k | s] * hi;
                        x[m][k | s] = a[k | s] * hi + b[k]     * lo;
                    }
                }
            }
        }
        // stages 4..9: coeff from swizzled LDS; exchange via DPP or shfl
        #pragma unroll
        for (int i = 4; i < 10; ++i) {
            const int d = 1 << (i - 4);
            float a[16], b[16];
            const float* arow = &cf[(size_t)(i - 4) * 2048];
            const float* brow = arow + 1024;
            #pragma unroll
            for (int c = 0; c < 4; ++c) {
                f4 va = *reinterpret_cast<const f4*>(&arow[swz(lane * 16 + 4 * c)]);
                f4 vb = *reinterpret_cast<const f4*>(&brow[swz((lane ^ d) * 16 + 4 * c)]);
                a[4*c+0]=va.x; a[4*c+1]=va.y; a[4*c+2]=va.z; a[4*c+3]=va.w;
                b[4*c+0]=vb.x; b[4*c+1]=vb.y; b[4*c+2]=vb.z; b[4*c+3]=vb.w;
            }
            #pragma unroll
            for (int m = 0; m < 2; ++m) {
                #pragma unroll
                for (int k = 0; k < 16; ++k) {
                    float xp = (d == 1) ? dppx<0xB1>(x[m][k])
                             : (d == 2) ? dppx<0x4E>(x[m][k])
                             : (d == 8) ? dppx<0x128>(x[m][k])
                             : __shfl_xor(x[m][k], d, 64);
                    x[m][k] = a[k] * x[m][k] + b[k] * xp;
                }
            }
        }
    };

    const i4* srv = reinterpret_cast<const i4*>(src);
    const f4* scv = reinterpret_cast<const f4*>(scale);

    auto emit = [&](float (&x)[2][16], int s0) {
        // z -> swizzled wave-private LDS (in-wave lgkmcnt ordering suffices)
        #pragma unroll
        for (int h = 0; h < 2; ++h) {
            const float* xr = x[h];
            #pragma unroll
            for (int c = 0; c < 4; ++c) {
                int e = lane * 16 + 4 * c;
                f4 v = { xr[4*c+0], xr[4*c+1], xr[4*c+2], xr[4*c+3] };
                *reinterpret_cast<f4*>(&zw[h * 1024 + swz(e)]) = v;
            }
        }
        #pragma unroll 4
        for (int it = 0; it < 16; ++it) {
            int j4 = it * 64 + lane;
            i4 si = srv[j4];
            f4 sc = scv[j4];
            #pragma unroll
            for (int h = 0; h < 2; ++h) {
                const float* zh = &zw[h * 1024];
                f4 r;
                r.x = sc.x * zh[swz(si.x)];
                r.y = sc.y * zh[swz(si.y)];
                r.z = sc.z * zh[swz(si.z)];
                r.w = sc.w * zh[swz(si.w)];
                __builtin_nontemporal_store(
                    r, reinterpret_cast<f4*>(out + (size_t)(s0 + h) * 4096) + j4);
            }
        }
    };

    butterfly(xA);
    emit(xA, sb);          // pass-A stores drain while pass-B computes
    butterfly(xB);
    emit(xB, sb + 2);
}

extern "C" void kernel_launch(void* const* d_in, const int* in_sizes, int n_in,
                              void* d_out, int out_size, void* d_ws, size_t ws_size,
                              hipStream_t stream) {
    const float* inp  = (const float*)d_in[0];   // (8192, 1024) f32
    const float* lp   = (const float*)d_in[1];   // (24, 4096)  f32
    const int*   orow = (const int*)d_in[2];     // (4096,)     i32
    float* out = (float*)d_out;                  // (8192, 4096) f32

    float* scale = (float*)d_ws;                       // 4096 f32
    int*   src   = (int*)((char*)d_ws + 4096 * 4);     // 4096 i32

    bfly_prep<<<16, 256, 0, stream>>>(lp, orow, scale, src);
    bfly_main<<<512, 256, 0, stream>>>(inp, lp, scale, src, out);
}

// Round 6
// 52.506 us; speedup vs baseline: 1.1113x; 1.0360x over previous
//
#include <hip/hip_runtime.h>

// OurButterflyLayer: N=4096, LOGN=12, IN=1024, OUT=4096, BATCH=8192
//
// out[s,j] = scale[j] * z_s[src[j]],  z_s = 10-stage butterfly (stages 0..9)
// on the 1024-float input row s; stages 10,11 + out-row gather fold into
// per-output (scale, src) pairs (elements >=1024 stay zero through stages
// 0..9 since all strides < 1024).
//
// Round-6: occupancy fix. 1024 blocks x 256 thr (4 blocks/CU = 16 waves/CU),
// 2 samples/wave. Stage 5..9 coeffs in 40 KB swizzled LDS (region reused as
// paired-z scratch); stages 0..4 coeffs from L1-hot global. Exchanges:
// verified DPP for d=1,2,8; verified __shfl_xor for d=4,16,32. Paired float2
// z-gather: one ds_read_b64 serves both samples.

typedef float f4 __attribute__((ext_vector_type(4)));
typedef float f2 __attribute__((ext_vector_type(2)));
typedef int   i4 __attribute__((ext_vector_type(4)));

__device__ __forceinline__ int swz(int e) {
    // XOR float-index bits [6:5] into [3:2]: keeps float4 alignment; makes
    // 64B-stride LDS coeff accesses bank-conflict-free.
    return e ^ (((e >> 5) & 3) << 2);
}

template<int CTRL>
__device__ __forceinline__ float dppx(float x) {
    int xi = __builtin_bit_cast(int, x);
    int r  = __builtin_amdgcn_update_dpp(xi, xi, CTRL, 0xF, 0xF, true);
    return __builtin_bit_cast(float, r);
}
// ctrl: quad_perm(1,0,3,2)=0xB1 (lane^1), quad_perm(2,3,0,1)=0x4E (lane^2),
// row_ror:8=0x128 (lane^8 within 16-lane row). All three verified in R4.

__global__ void __launch_bounds__(256) bfly_prep(
    const float* __restrict__ lp, const int* __restrict__ orow,
    float* __restrict__ scale, int* __restrict__ src2)
{
    int j = blockIdx.x * 256 + threadIdx.x;
    if (j >= 4096) return;
    int r = orow[j];
    int c = r & 1023;
    int u = r & 2047;
    const float* A10 = lp + 20 * 4096;
    const float* B10 = lp + 21 * 4096;
    const float* A11 = lp + 22 * 4096;
    const float* B11 = lp + 23 * 4096;
    float f11 = (r & 2048) ? B11[u] : A11[u];
    float f10 = (r & 1024) ? B10[c] : A10[c];
    scale[j] = f11 * f10;
    // pre-swizzled float2-index into the paired z buffer:
    // pz(c) = c ^ (((c>>4)&7)<<1)  (pair-preserving bank spread)
    src2[j] = c ^ (((c >> 4) & 7) << 1);
}

__global__ void __launch_bounds__(256, 4) bfly_main(
    const float* __restrict__ inp, const float* __restrict__ lp,
    const float* __restrict__ scale, const int* __restrict__ src2,
    float* __restrict__ out)
{
    // 10 rows x 1024 floats: a,b for stages 5..9 (swizzled). Reused as zbuf.
    __shared__ __align__(16) float cf[10 * 1024];
    const int t = threadIdx.x;
    const int wave = t >> 6, lane = t & 63;

    // cooperative coeff staging: lp rows 10..19, first 1024 floats of each
    #pragma unroll
    for (int q = 0; q < 10; ++q) {
        const f4 v = *reinterpret_cast<const f4*>(lp + (size_t)(10 + q) * 4096 + t * 4);
        *reinterpret_cast<f4*>(&cf[q * 1024 + swz(t * 4)]) = v;
    }

    const int sBase = blockIdx.x * 8 + wave * 2;   // 2 samples per wave
    float x[2][16];
    #pragma unroll
    for (int m = 0; m < 2; ++m) {
        const f4* p = reinterpret_cast<const f4*>(inp + (size_t)(sBase + m) * 1024 + lane * 16);
        #pragma unroll
        for (int c = 0; c < 4; ++c) {
            f4 v = __builtin_nontemporal_load(p + c);
            x[m][4*c+0] = v.x; x[m][4*c+1] = v.y; x[m][4*c+2] = v.z; x[m][4*c+3] = v.w;
        }
    }

    __syncthreads();   // cf ready

    // stages 0..3: coeff from global (L1-hot), pairs inside the lane's 16 regs
    #pragma unroll
    for (int i = 0; i < 4; ++i) {
        float a[16], b[16];
        const f4* A = reinterpret_cast<const f4*>(lp + (size_t)(2*i)   * 4096 + lane * 16);
        const f4* B = reinterpret_cast<const f4*>(lp + (size_t)(2*i+1) * 4096 + lane * 16);
        #pragma unroll
        for (int c = 0; c < 4; ++c) {
            f4 va = A[c], vb = B[c];
            a[4*c+0]=va.x; a[4*c+1]=va.y; a[4*c+2]=va.z; a[4*c+3]=va.w;
            b[4*c+0]=vb.x; b[4*c+1]=vb.y; b[4*c+2]=vb.z; b[4*c+3]=vb.w;
        }
        const int s = 1 << i;
        #pragma unroll
        for (int m = 0; m < 2; ++m) {
            #pragma unroll
            for (int k = 0; k < 16; ++k) {
                if (!(k & s)) {
                    float lo = x[m][k], hi = x[m][k | s];
                    x[m][k]     = a[k]     * lo + b[k | s] * hi;
                    x[m][k | s] = a[k | s] * hi + b[k]     * lo;
                }
            }
        }
    }

    // stage 4 (d=1): coeff from global rows 8,9; exchange via DPP quad_perm
    {
        float a[16], b[16];
        const f4* A = reinterpret_cast<const f4*>(lp + (size_t)8 * 4096 + lane * 16);
        const f4* B = reinterpret_cast<const f4*>(lp + (size_t)9 * 4096 + (lane ^ 1) * 16);
        #pragma unroll
        for (int c = 0; c < 4; ++c) {
            f4 va = A[c], vb = B[c];
            a[4*c+0]=va.x; a[4*c+1]=va.y; a[4*c+2]=va.z; a[4*c+3]=va.w;
            b[4*c+0]=vb.x; b[4*c+1]=vb.y; b[4*c+2]=vb.z; b[4*c+3]=vb.w;
        }
        #pragma unroll
        for (int m = 0; m < 2; ++m)
            #pragma unroll
            for (int k = 0; k < 16; ++k) {
                float v = x[m][k];
                x[m][k] = a[k] * v + b[k] * dppx<0xB1>(v);
            }
    }

    // stages 5..9: coeff from swizzled LDS; exchange via verified DPP/shfl
    #pragma unroll
    for (int i = 5; i < 10; ++i) {
        const int d = 1 << (i - 4);
        float a[16], b[16];
        const float* arow = &cf[(size_t)(i - 5) * 2048];
        const float* brow = arow + 1024;
        #pragma unroll
        for (int c = 0; c < 4; ++c) {
            f4 va = *reinterpret_cast<const f4*>(&arow[swz(lane * 16 + 4 * c)]);
            f4 vb = *reinterpret_cast<const f4*>(&brow[swz((lane ^ d) * 16 + 4 * c)]);
            a[4*c+0]=va.x; a[4*c+1]=va.y; a[4*c+2]=va.z; a[4*c+3]=va.w;
            b[4*c+0]=vb.x; b[4*c+1]=vb.y; b[4*c+2]=vb.z; b[4*c+3]=vb.w;
        }
        #pragma unroll
        for (int m = 0; m < 2; ++m) {
            #pragma unroll
            for (int k = 0; k < 16; ++k) {
                float v = x[m][k];
                float xp = (d == 2) ? dppx<0x4E>(v)
                         : (d == 8) ? dppx<0x128>(v)
                         :            __shfl_xor(v, d, 64);   // d = 4, 16, 32
                x[m][k] = a[k] * v + b[k] * xp;
            }
        }
    }

    __syncthreads();   // all coeff reads done; reuse cf as paired z scratch

    float* zz = &cf[(size_t)wave * 2048];      // 1024 float2 per wave (8 KB)
    const int km0 = (lane & 7) << 1;           // pair-preserving write swizzle

    // interleaved z write: float2-slot pi = pz(c) for c = lane*16+k
    #pragma unroll
    for (int k = 0; k < 16; k += 2) {
        int pi = lane * 16 + (k ^ km0);
        f4 v = { x[0][k], x[1][k], x[0][k+1], x[1][k+1] };
        *reinterpret_cast<f4*>(&zz[2 * pi]) = v;
    }

    // gather: one b64 read serves both samples (wave-private region; same-
    // wave DS ordering keeps write->read safe without a barrier)
    const i4* srv = reinterpret_cast<const i4*>(src2);
    const f4* scv = reinterpret_cast<const f4*>(scale);
    float* o0 = out + (size_t)sBase * 4096;
    float* o1 = out + (size_t)(sBase + 1) * 4096;
    #pragma unroll 4
    for (int it = 0; it < 16; ++it) {
        int j4 = it * 64 + lane;
        i4 si = srv[j4];
        f4 sc = scv[j4];
        f2 vx = *reinterpret_cast<const f2*>(&zz[2 * si.x]);
        f2 vy = *reinterpret_cast<const f2*>(&zz[2 * si.y]);
        f2 vz = *reinterpret_cast<const f2*>(&zz[2 * si.z]);
        f2 vw = *reinterpret_cast<const f2*>(&zz[2 * si.w]);
        f4 r0 = { sc.x * vx.x, sc.y * vy.x, sc.z * vz.x, sc.w * vw.x };
        f4 r1 = { sc.x * vx.y, sc.y * vy.y, sc.z * vz.y, sc.w * vw.y };
        __builtin_nontemporal_store(r0, reinterpret_cast<f4*>(o0) + j4);
        __builtin_nontemporal_store(r1, reinterpret_cast<f4*>(o1) + j4);
    }
}

extern "C" void kernel_launch(void* const* d_in, const int* in_sizes, int n_in,
                              void* d_out, int out_size, void* d_ws, size_t ws_size,
                              hipStream_t stream) {
    const float* inp  = (const float*)d_in[0];   // (8192, 1024) f32
    const float* lp   = (const float*)d_in[1];   // (24, 4096)  f32
    const int*   orow = (const int*)d_in[2];     // (4096,)     i32
    float* out = (float*)d_out;                  // (8192, 4096) f32

    float* scale = (float*)d_ws;                       // 4096 f32
    int*   src2  = (int*)((char*)d_ws + 4096 * 4);     // 4096 i32 (swizzled)

    bfly_prep<<<16, 256, 0, stream>>>(lp, orow, scale, src2);
    bfly_main<<<1024, 256, 0, stream>>>(inp, lp, scale, src2, out);
}

// Round 7
// 44.603 us; speedup vs baseline: 1.3082x; 1.1772x over previous
//
#include <hip/hip_runtime.h>

// OurButterflyLayer: N=4096, LOGN=12, IN=1024, OUT=4096, BATCH=8192
//
// out[s,j] = scale[j] * z_s[src[j]],  z_s = 10-stage butterfly (stages 0..9)
// on the 1024-float input row s; stages 10,11 + out-row gather fold into
// per-output (scale, src) pairs (elements >=1024 stay zero through stages
// 0..9 since all strides < 1024).
//
// Round-7: R6 structure (1024 blocks x 256 thr = 16 waves/CU, 2 samples/wave,
// stage-5..9 coeffs in 40 KB swizzled LDS reused as paired-z scratch, verified
// DPP d=1,2,8 + shfl d=4,16,32, paired float2 z-gather) with the store path
// fixed: PLAIN stores/loads (retire at L2, not HBM -> no in-order vmcnt
// chaining behind write drain) + 1-deep pipelined epilogue loads.

typedef float f4 __attribute__((ext_vector_type(4)));
typedef float f2 __attribute__((ext_vector_type(2)));
typedef int   i4 __attribute__((ext_vector_type(4)));

__device__ __forceinline__ int swz(int e) {
    // XOR float-index bits [6:5] into [3:2]: keeps float4 alignment; makes
    // 64B-stride LDS coeff accesses bank-conflict-free.
    return e ^ (((e >> 5) & 3) << 2);
}

template<int CTRL>
__device__ __forceinline__ float dppx(float x) {
    int xi = __builtin_bit_cast(int, x);
    int r  = __builtin_amdgcn_update_dpp(xi, xi, CTRL, 0xF, 0xF, true);
    return __builtin_bit_cast(float, r);
}
// ctrl: quad_perm(1,0,3,2)=0xB1 (lane^1), quad_perm(2,3,0,1)=0x4E (lane^2),
// row_ror:8=0x128 (lane^8 within 16-lane row). All verified in R4/R6.

__global__ void __launch_bounds__(256) bfly_prep(
    const float* __restrict__ lp, const int* __restrict__ orow,
    float* __restrict__ scale, int* __restrict__ src2)
{
    int j = blockIdx.x * 256 + threadIdx.x;
    if (j >= 4096) return;
    int r = orow[j];
    int c = r & 1023;
    int u = r & 2047;
    const float* A10 = lp + 20 * 4096;
    const float* B10 = lp + 21 * 4096;
    const float* A11 = lp + 22 * 4096;
    const float* B11 = lp + 23 * 4096;
    float f11 = (r & 2048) ? B11[u] : A11[u];
    float f10 = (r & 1024) ? B10[c] : A10[c];
    scale[j] = f11 * f10;
    // pre-swizzled float2-index into the paired z buffer:
    // pz(c) = c ^ (((c>>4)&7)<<1)  (pair-preserving bank spread)
    src2[j] = c ^ (((c >> 4) & 7) << 1);
}

__global__ void __launch_bounds__(256, 4) bfly_main(
    const float* __restrict__ inp, const float* __restrict__ lp,
    const float* __restrict__ scale, const int* __restrict__ src2,
    float* __restrict__ out)
{
    // 10 rows x 1024 floats: a,b for stages 5..9 (swizzled). Reused as zbuf.
    __shared__ __align__(16) float cf[10 * 1024];
    const int t = threadIdx.x;
    const int wave = t >> 6, lane = t & 63;

    // cooperative coeff staging: lp rows 10..19, first 1024 floats of each
    #pragma unroll
    for (int q = 0; q < 10; ++q) {
        const f4 v = *reinterpret_cast<const f4*>(lp + (size_t)(10 + q) * 4096 + t * 4);
        *reinterpret_cast<f4*>(&cf[q * 1024 + swz(t * 4)]) = v;
    }

    const int sBase = blockIdx.x * 8 + wave * 2;   // 2 samples per wave
    float x[2][16];
    #pragma unroll
    for (int m = 0; m < 2; ++m) {
        const f4* p = reinterpret_cast<const f4*>(inp + (size_t)(sBase + m) * 1024 + lane * 16);
        #pragma unroll
        for (int c = 0; c < 4; ++c) {
            f4 v = p[c];
            x[m][4*c+0] = v.x; x[m][4*c+1] = v.y; x[m][4*c+2] = v.z; x[m][4*c+3] = v.w;
        }
    }

    __syncthreads();   // cf ready

    // stages 0..3: coeff from global (L1-hot), pairs inside the lane's 16 regs
    #pragma unroll
    for (int i = 0; i < 4; ++i) {
        float a[16], b[16];
        const f4* A = reinterpret_cast<const f4*>(lp + (size_t)(2*i)   * 4096 + lane * 16);
        const f4* B = reinterpret_cast<const f4*>(lp + (size_t)(2*i+1) * 4096 + lane * 16);
        #pragma unroll
        for (int c = 0; c < 4; ++c) {
            f4 va = A[c], vb = B[c];
            a[4*c+0]=va.x; a[4*c+1]=va.y; a[4*c+2]=va.z; a[4*c+3]=va.w;
            b[4*c+0]=vb.x; b[4*c+1]=vb.y; b[4*c+2]=vb.z; b[4*c+3]=vb.w;
        }
        const int s = 1 << i;
        #pragma unroll
        for (int m = 0; m < 2; ++m) {
            #pragma unroll
            for (int k = 0; k < 16; ++k) {
                if (!(k & s)) {
                    float lo = x[m][k], hi = x[m][k | s];
                    x[m][k]     = a[k]     * lo + b[k | s] * hi;
                    x[m][k | s] = a[k | s] * hi + b[k]     * lo;
                }
            }
        }
    }

    // stage 4 (d=1): coeff from global rows 8,9; exchange via DPP quad_perm
    {
        float a[16], b[16];
        const f4* A = reinterpret_cast<const f4*>(lp + (size_t)8 * 4096 + lane * 16);
        const f4* B = reinterpret_cast<const f4*>(lp + (size_t)9 * 4096 + (lane ^ 1) * 16);
        #pragma unroll
        for (int c = 0; c < 4; ++c) {
            f4 va = A[c], vb = B[c];
            a[4*c+0]=va.x; a[4*c+1]=va.y; a[4*c+2]=va.z; a[4*c+3]=va.w;
            b[4*c+0]=vb.x; b[4*c+1]=vb.y; b[4*c+2]=vb.z; b[4*c+3]=vb.w;
        }
        #pragma unroll
        for (int m = 0; m < 2; ++m)
            #pragma unroll
            for (int k = 0; k < 16; ++k) {
                float v = x[m][k];
                x[m][k] = a[k] * v + b[k] * dppx<0xB1>(v);
            }
    }

    // stages 5..9: coeff from swizzled LDS; exchange via verified DPP/shfl
    #pragma unroll
    for (int i = 5; i < 10; ++i) {
        const int d = 1 << (i - 4);
        float a[16], b[16];
        const float* arow = &cf[(size_t)(i - 5) * 2048];
        const float* brow = arow + 1024;
        #pragma unroll
        for (int c = 0; c < 4; ++c) {
            f4 va = *reinterpret_cast<const f4*>(&arow[swz(lane * 16 + 4 * c)]);
            f4 vb = *reinterpret_cast<const f4*>(&brow[swz((lane ^ d) * 16 + 4 * c)]);
            a[4*c+0]=va.x; a[4*c+1]=va.y; a[4*c+2]=va.z; a[4*c+3]=va.w;
            b[4*c+0]=vb.x; b[4*c+1]=vb.y; b[4*c+2]=vb.z; b[4*c+3]=vb.w;
        }
        #pragma unroll
        for (int m = 0; m < 2; ++m) {
            #pragma unroll
            for (int k = 0; k < 16; ++k) {
                float v = x[m][k];
                float xp = (d == 2) ? dppx<0x4E>(v)
                         : (d == 8) ? dppx<0x128>(v)
                         :            __shfl_xor(v, d, 64);   // d = 4, 16, 32
                x[m][k] = a[k] * v + b[k] * xp;
            }
        }
    }

    __syncthreads();   // all coeff reads done; reuse cf as paired z scratch

    float* zz = &cf[(size_t)wave * 2048];      // 1024 float2 per wave (8 KB)
    const int km0 = (lane & 7) << 1;           // pair-preserving write swizzle

    // interleaved z write: float2-slot pi = pz(c) for c = lane*16+k
    #pragma unroll
    for (int k = 0; k < 16; k += 2) {
        int pi = lane * 16 + (k ^ km0);
        f4 v = { x[0][k], x[1][k], x[0][k+1], x[1][k+1] };
        *reinterpret_cast<f4*>(&zz[2 * pi]) = v;
    }

    // epilogue: one b64 LDS read serves both samples; srv/scv loads pipelined
    // 1 deep so each iteration's loads are issued BEFORE the previous
    // iteration's stores (keeps load-use waits off the store queue).
    const i4* srv = reinterpret_cast<const i4*>(src2);
    const f4* scv = reinterpret_cast<const f4*>(scale);
    f4* o0 = reinterpret_cast<f4*>(out + (size_t)sBase * 4096);
    f4* o1 = reinterpret_cast<f4*>(out + (size_t)(sBase + 1) * 4096);

    i4 si = srv[lane];
    f4 sc = scv[lane];
    #pragma unroll
    for (int it = 0; it < 16; ++it) {
        i4 si_c = si;
        f4 sc_c = sc;
        if (it + 1 < 16) {                      // prefetch next iteration
            si = srv[(it + 1) * 64 + lane];
            sc = scv[(it + 1) * 64 + lane];
        }
        int j4 = it * 64 + lane;
        f2 vx = *reinterpret_cast<const f2*>(&zz[2 * si_c.x]);
        f2 vy = *reinterpret_cast<const f2*>(&zz[2 * si_c.y]);
        f2 vz = *reinterpret_cast<const f2*>(&zz[2 * si_c.z]);
        f2 vw = *reinterpret_cast<const f2*>(&zz[2 * si_c.w]);
        f4 r0 = { sc_c.x * vx.x, sc_c.y * vy.x, sc_c.z * vz.x, sc_c.w * vw.x };
        f4 r1 = { sc_c.x * vx.y, sc_c.y * vy.y, sc_c.z * vz.y, sc_c.w * vw.y };
        o0[j4] = r0;
        o1[j4] = r1;
    }
}

extern "C" void kernel_launch(void* const* d_in, const int* in_sizes, int n_in,
                              void* d_out, int out_size, void* d_ws, size_t ws_size,
                              hipStream_t stream) {
    const float* inp  = (const float*)d_in[0];   // (8192, 1024) f32
    const float* lp   = (const float*)d_in[1];   // (24, 4096)  f32
    const int*   orow = (const int*)d_in[2];     // (4096,)     i32
    float* out = (float*)d_out;                  // (8192, 4096) f32

    float* scale = (float*)d_ws;                       // 4096 f32
    int*   src2  = (int*)((char*)d_ws + 4096 * 4);     // 4096 i32 (swizzled)

    bfly_prep<<<16, 256, 0, stream>>>(lp, orow, scale, src2);
    bfly_main<<<1024, 256, 0, stream>>>(inp, lp, scale, src2, out);
}